// Round 5
// baseline (320.065 us; speedup 1.0000x reference)
//
#include <hip/hip_runtime.h>
#include <hip/hip_bf16.h>

typedef __attribute__((ext_vector_type(8))) short short8;
typedef __attribute__((ext_vector_type(4))) float f32x4;

#define BM 128
#define BN 128
#define BK 64
#define KDIM 7168
#define NDIM 18432
#define SN 56            // KDIM/128 scale cols
#define NTK 112          // KDIM/BK

static __device__ __forceinline__ short bfb(float f) {
    __hip_bfloat16 h = __float2bfloat16(f);
    return __builtin_bit_cast(short, h);
}

// ---- pre-kernel: A fp32 -> bf16, tile-major, inverse-XOR-swizzled so the
// GEMM can global_load_lds it linearly and read with the XOR formula.
// unit g = ((mt*NTK + kt)*1024 + r*8 + slot); content = A[mt*128+r][kt*64 + (slot^(r&7))*8 .. +8)
extern "C" __global__ void __launch_bounds__(256)
a_permute(const float* __restrict__ A, __hip_bfloat16* __restrict__ Abt, int nunits) {
    int g = blockIdx.x * blockDim.x + threadIdx.x;
    if (g >= nunits) return;
    int u    = g & 1023;
    int t    = g >> 10;
    int ktt  = t % NTK;
    int mt   = t / NTK;
    int r    = u >> 3;
    int slot = u & 7;
    int row  = mt * BM + r;
    int col  = ktt * BK + ((slot ^ (r & 7)) << 3);
    const float* p = A + (size_t)row * KDIM + col;
    f32x4 v0 = *(const f32x4*)p;
    f32x4 v1 = *(const f32x4*)(p + 4);
    short8 o;
#pragma unroll
    for (int j = 0; j < 4; ++j) { o[j] = bfb(v0[j]); o[j + 4] = bfb(v1[j]); }
    *(short8*)(Abt + (size_t)g * 8) = o;
}

// AMODE 1: A via global_load_lds from pre-permuted Abt.
// AMODE 0: fallback, A fp32 reg-staged (no ws needed).
template <int AMODE>
__global__ void __launch_bounds__(512, 4)
fp8lin_gemm(const float* __restrict__ A,          // [M][K] fp32
            const char*  __restrict__ Abt,        // pre-permuted bf16 tiles (ws)
            const float* __restrict__ W,          // [N][K] fp32
            const float* __restrict__ S,          // [N/128][K/128]
            float* __restrict__ C,                // [M][N]
            int M)
{
    const int ntile_m = M / BM;            // 4
    const int ntile_n = NDIM / BN;         // 144
    const int nwg = ntile_m * ntile_n;     // 576

    // chunked XCD swizzle; m-minor so the 4 blocks sharing a W panel sit on
    // the same XCD's L2.
    int orig = (int)blockIdx.x;
    int q = nwg >> 3;
    int lid = (orig & 7) * q + (orig >> 3);

    const int tm = lid % ntile_m;
    const int tn = lid / ntile_m;
    const int m0 = tm * BM;
    const int n0 = tn * BN;

    const int tid  = threadIdx.x;
    const int lane = tid & 63;
    const int wid  = tid >> 6;      // 8 waves: 2(M) x 4(N)
    const int wm   = wid >> 2;
    const int wn   = wid & 3;

    __shared__ char ldsA[2][BM * BK * 2];   // bf16 A tiles, 16 KiB each
    __shared__ char ldsW[2][BN * BK * 2];   // bf16 dequant W tiles, 16 KiB each

    // staging geometry (W, and A in AMODE 0): unit u = c*512+tid;
    // r = u>>3, slot = u&7; XOR-swizzled LDS byte.
    int st_r[2], st_sl[2], st_byte[2];
#pragma unroll
    for (int c = 0; c < 2; ++c) {
        int u = c * 512 + tid;
        int r  = u >> 3;
        int sl = u & 7;
        st_r[c]    = r;
        st_sl[c]   = sl;
        st_byte[c] = r * (BK * 2) + ((sl ^ (r & 7)) << 4);
    }

    const float* Afp = A + (size_t)m0 * KDIM;
    const float* Wb  = W + (size_t)n0 * KDIM;

    f32x4 rw[2][2];        // W fp32 staging (one set; refilled after WRITES)
    f32x4 rafp[2][4];      // A fp32 staging (AMODE 0 only)

    auto AGL = [&](int kt_, int buf) {   // async A: global -> LDS, 2 insts/wave
        const char* src = Abt + (((size_t)(tm * NTK + kt_)) << 14);
#pragma unroll
        for (int c = 0; c < 2; ++c) {
            int ub = wid * 128 + c * 64;
            __builtin_amdgcn_global_load_lds(
                (const __attribute__((address_space(1))) void*)(src + (size_t)(ub + lane) * 16),
                (__attribute__((address_space(3))) void*)(&ldsA[buf][ub * 16]),
                16, 0, 0);
        }
    };

    auto WLD = [&](int kt_) {            // W fp32 -> regs (4 loads)
        const int kof = kt_ * BK;
#pragma unroll
        for (int c = 0; c < 2; ++c) {
            const float* pw = Wb + (size_t)st_r[c] * KDIM + kof + st_sl[c] * 8;
            rw[c][0] = *(const f32x4*)pw;
            rw[c][1] = *(const f32x4*)(pw + 4);
        }
    };

    auto ALD = [&](int kt_) {            // AMODE 0: A fp32 -> regs (4 loads)
        const int kof = kt_ * BK;
#pragma unroll
        for (int c = 0; c < 2; ++c) {
            const float* pa = Afp + (size_t)st_r[c] * KDIM + kof + st_sl[c] * 8;
            rafp[c][0] = *(const f32x4*)pa;
            rafp[c][1] = *(const f32x4*)(pa + 4);
        }
    };

    auto WRITES = [&](int buf, float s) {  // convert + ds_write (W, and A if AMODE0)
#pragma unroll
        for (int c = 0; c < 2; ++c) {
            short8 vw;
#pragma unroll
            for (int j = 0; j < 4; ++j) {
                vw[j]     = bfb(rw[c][0][j] * s);
                vw[j + 4] = bfb(rw[c][1][j] * s);
            }
            *(short8*)(&ldsW[buf][st_byte[c]]) = vw;
            if (AMODE == 0) {
                short8 va;
#pragma unroll
                for (int j = 0; j < 4; ++j) {
                    va[j]     = bfb(rafp[c][0][j]);
                    va[j + 4] = bfb(rafp[c][1][j]);
                }
                *(short8*)(&ldsA[buf][st_byte[c]]) = va;
            }
        }
    };

    f32x4 acc[4][2];
#pragma unroll
    for (int i = 0; i < 4; ++i)
#pragma unroll
        for (int j = 0; j < 2; ++j)
            acc[i][j] = f32x4{0.f, 0.f, 0.f, 0.f};

    const int l15 = lane & 15;
    const int lq  = lane >> 4;

    auto COMPUTE = [&](int buf) {
        const char* la = ldsA[buf];
        const char* lb = ldsW[buf];
#pragma unroll
        for (int kk = 0; kk < 2; ++kk) {
            int kc = kk * 4 + lq;
            short8 af[4], bq[2];
#pragma unroll
            for (int i = 0; i < 4; ++i) {
                int r = wm * 64 + i * 16 + l15;
                af[i] = *(const short8*)(la + r * (BK * 2) + ((kc ^ (r & 7)) << 4));
            }
#pragma unroll
            for (int j = 0; j < 2; ++j) {
                int r = wn * 32 + j * 16 + l15;
                bq[j] = *(const short8*)(lb + r * (BK * 2) + ((kc ^ (r & 7)) << 4));
            }
            __builtin_amdgcn_s_setprio(1);
#pragma unroll
            for (int i = 0; i < 4; ++i)
#pragma unroll
                for (int j = 0; j < 2; ++j)
                    acc[i][j] = __builtin_amdgcn_mfma_f32_16x16x32_bf16(af[i], bq[j], acc[i][j], 0, 0, 0);
            __builtin_amdgcn_s_setprio(0);
        }
    };

    const float* Srow = S + (size_t)tn * SN;

    // ---- prologue: tile 0 into buf 0, tile-1 W loads in flight
    if (AMODE) AGL(0, 0); else ALD(0);
    WLD(0);
    WRITES(0, Srow[0]);        // compiler-inserted vmcnt drains prologue loads
    if (AMODE == 0) ALD(1);
    WLD(1);
    __builtin_amdgcn_sched_barrier(0);
    asm volatile("s_waitcnt vmcnt(8) lgkmcnt(0)" ::: "memory"); // keep tile-1 loads in flight
    __builtin_amdgcn_s_barrier();
    __builtin_amdgcn_sched_barrier(0);

    // ---- main loop: 1 barrier/step, counted vmcnt (never 0)
    for (int kt = 0; kt < NTK; ++kt) {
        const int cur = kt & 1;
        const int nxt = cur ^ 1;
        const int ka  = (kt + 1 < NTK) ? kt + 1 : NTK - 1;   // clamped (dup load, unused)
        const int kw  = (kt + 2 < NTK) ? kt + 2 : NTK - 1;
        const int sidx = (ka >> 1) < SN ? (ka >> 1) : SN - 1;

        if (AMODE) AGL(ka, nxt);     // async A for next tile
        COMPUTE(cur);
        WRITES(nxt, Srow[sidx]);     // auto-waits only the consumed W regs
        if (AMODE == 0) ALD(kw);
        WLD(kw);                     // refill; stays in flight across barrier
        __builtin_amdgcn_sched_barrier(0);
        if (AMODE)
            asm volatile("s_waitcnt vmcnt(4) lgkmcnt(0)" ::: "memory"); // A-gload done; 4 W loads flying
        else
            asm volatile("s_waitcnt vmcnt(8) lgkmcnt(0)" ::: "memory"); // 8 next loads flying
        __builtin_amdgcn_s_barrier();
        __builtin_amdgcn_sched_barrier(0);
    }

    // ---- epilogue: C/D layout col=lane&15, row=(lane>>4)*4+r
    float* Cb = C + (size_t)(m0 + wm * 64) * NDIM + (n0 + wn * 32);
    const int crow = lq * 4;
#pragma unroll
    for (int i = 0; i < 4; ++i) {
#pragma unroll
        for (int r = 0; r < 4; ++r) {
            float* Cr = Cb + (size_t)(i * 16 + crow + r) * NDIM + l15;
#pragma unroll
            for (int j = 0; j < 2; ++j)
                Cr[j * 16] = acc[i][j][r];
        }
    }
}

extern "C" void kernel_launch(void* const* d_in, const int* in_sizes, int n_in,
                              void* d_out, int out_size, void* d_ws, size_t ws_size,
                              hipStream_t stream) {
    const float* inp = (const float*)d_in[0];   // [1,512,7168] fp32
    const float* w   = (const float*)d_in[1];   // [18432,7168] fp32
    const float* s   = (const float*)d_in[2];   // [144,56] fp32
    float* out       = (float*)d_out;           // [1,512,18432] fp32

    int M = in_sizes[0] / KDIM;                 // 512
    int grid = (M / BM) * (NDIM / BN);          // 576
    int nunits = (M / BM) * NTK * 1024;
    size_t need = (size_t)nunits * 16;

    if (ws_size >= need) {
        __hip_bfloat16* abt = (__hip_bfloat16*)d_ws;
        hipLaunchKernelGGL(a_permute, dim3((nunits + 255) / 256), dim3(256), 0, stream,
                           inp, abt, nunits);
        hipLaunchKernelGGL((fp8lin_gemm<1>), dim3(grid), dim3(512), 0, stream,
                           inp, (const char*)abt, w, s, out, M);
    } else {
        hipLaunchKernelGGL((fp8lin_gemm<0>), dim3(grid), dim3(512), 0, stream,
                           inp, (const char*)nullptr, w, s, out, M);
    }
}

// Round 6
// 312.424 us; speedup vs baseline: 1.0245x; 1.0245x over previous
//
#include <hip/hip_runtime.h>
#include <hip/hip_bf16.h>

typedef __attribute__((ext_vector_type(8))) short short8;
typedef __attribute__((ext_vector_type(4))) float f32x4;
typedef __attribute__((ext_vector_type(16))) float f32x16;

#define BM 128
#define BN 128
#define BK 64
#define KDIM 7168
#define NDIM 18432
#define SN 56            // KDIM/128 scale cols
#define NTK 112          // KDIM/BK

static __device__ __forceinline__ short bfb(float f) {
    __hip_bfloat16 h = __float2bfloat16(f);
    return __builtin_bit_cast(short, h);
}

// ---- pre-kernel: A fp32 -> bf16, tile-major, inverse-XOR-swizzled so the
// GEMM can global_load_lds it linearly and read with the XOR formula.
// unit g = ((mt*NTK + kt)*1024 + r*8 + slot); content = A[mt*128+r][kt*64 + (slot^(r&7))*8 .. +8)
extern "C" __global__ void __launch_bounds__(256)
a_permute(const float* __restrict__ A, __hip_bfloat16* __restrict__ Abt, int nunits) {
    int g = blockIdx.x * blockDim.x + threadIdx.x;
    if (g >= nunits) return;
    int u    = g & 1023;
    int t    = g >> 10;
    int ktt  = t % NTK;
    int mt   = t / NTK;
    int r    = u >> 3;
    int slot = u & 7;
    int row  = mt * BM + r;
    int col  = ktt * BK + ((slot ^ (r & 7)) << 3);
    const float* p = A + (size_t)row * KDIM + col;
    f32x4 v0 = *(const f32x4*)p;
    f32x4 v1 = *(const f32x4*)(p + 4);
    short8 o;
#pragma unroll
    for (int j = 0; j < 4; ++j) { o[j] = bfb(v0[j]); o[j + 4] = bfb(v1[j]); }
    *(short8*)(Abt + (size_t)g * 8) = o;
}

// AMODE 1: A via global_load_lds from pre-permuted Abt.
// AMODE 0: fallback, A fp32 reg-staged.
template <int AMODE>
__global__ void __launch_bounds__(256, 2)
fp8lin_gemm(const float* __restrict__ A,          // [M][K] fp32
            const char*  __restrict__ Abt,        // pre-permuted bf16 tiles (ws)
            const float* __restrict__ W,          // [N][K] fp32
            const float* __restrict__ S,          // [N/128][K/128]
            float* __restrict__ C,                // [M][N]
            int M)
{
    const int ntile_m = M / BM;            // 4
    const int ntile_n = NDIM / BN;         // 144
    const int nwg = ntile_m * ntile_n;     // 576

    // chunked XCD swizzle; m-minor so the 4 blocks sharing a W panel sit on
    // the same XCD's L2.
    int orig = (int)blockIdx.x;
    int q = nwg >> 3;
    int lid = (orig & 7) * q + (orig >> 3);

    const int tm = lid % ntile_m;
    const int tn = lid / ntile_m;
    const int m0 = tm * BM;
    const int n0 = tn * BN;

    const int tid  = threadIdx.x;
    const int lane = tid & 63;
    const int wid  = tid >> 6;      // 4 waves: 2(M) x 2(N), wave tile 64x64
    const int wm   = wid >> 1;
    const int wn   = wid & 1;

    __shared__ char ldsA[2][BM * BK * 2];   // bf16 A tiles, 16 KiB each
    __shared__ char ldsW[2][BN * BK * 2];   // bf16 dequant W tiles, 16 KiB each

    // W staging geometry: unit u = c*256+tid (c=0..3); r=u>>3, slot=u&7.
    int st_r[4], st_sl[4], st_byte[4];
#pragma unroll
    for (int c = 0; c < 4; ++c) {
        int u = c * 256 + tid;
        int r  = u >> 3;
        int sl = u & 7;
        st_r[c]    = r;
        st_sl[c]   = sl;
        st_byte[c] = r * (BK * 2) + ((sl ^ (r & 7)) << 4);
    }

    const float* Afp = A + (size_t)m0 * KDIM;
    const float* Wb  = W + (size_t)n0 * KDIM;

    f32x4 rw[4][2];        // W fp32 staging regs (distance-2 prefetch)
    f32x4 rafp[4][2];      // A fp32 staging (AMODE 0 only)

    auto AGL = [&](int kt_, int buf) {   // async A: global -> LDS, 4 insts/wave
        const char* src = Abt + (((size_t)(tm * NTK + kt_)) << 14);
#pragma unroll
        for (int c = 0; c < 4; ++c) {
            int ub = c * 256 + wid * 64;
            __builtin_amdgcn_global_load_lds(
                (const __attribute__((address_space(1))) void*)(src + (size_t)(ub + lane) * 16),
                (__attribute__((address_space(3))) void*)(&ldsA[buf][ub * 16]),
                16, 0, 0);
        }
    };

    auto WLD = [&](int kt_) {            // W fp32 -> regs (8 x dwordx4)
        const int kof = kt_ * BK;
#pragma unroll
        for (int c = 0; c < 4; ++c) {
            const float* pw = Wb + (size_t)st_r[c] * KDIM + kof + st_sl[c] * 8;
            rw[c][0] = *(const f32x4*)pw;
            rw[c][1] = *(const f32x4*)(pw + 4);
        }
    };

    auto ALD = [&](int kt_) {            // AMODE 0: A fp32 -> regs
        const int kof = kt_ * BK;
#pragma unroll
        for (int c = 0; c < 4; ++c) {
            const float* pa = Afp + (size_t)st_r[c] * KDIM + kof + st_sl[c] * 8;
            rafp[c][0] = *(const f32x4*)pa;
            rafp[c][1] = *(const f32x4*)(pa + 4);
        }
    };

    auto WRITES = [&](int buf, float s) {  // dequant convert + ds_write
#pragma unroll
        for (int c = 0; c < 4; ++c) {
            short8 vw;
#pragma unroll
            for (int j = 0; j < 4; ++j) {
                vw[j]     = bfb(rw[c][0][j] * s);
                vw[j + 4] = bfb(rw[c][1][j] * s);
            }
            *(short8*)(&ldsW[buf][st_byte[c]]) = vw;
            if (AMODE == 0) {
                short8 va;
#pragma unroll
                for (int j = 0; j < 4; ++j) {
                    va[j]     = bfb(rafp[c][0][j]);
                    va[j + 4] = bfb(rafp[c][1][j]);
                }
                *(short8*)(&ldsA[buf][st_byte[c]]) = va;
            }
        }
    };

    f32x16 acc[2][2];
#pragma unroll
    for (int i = 0; i < 2; ++i)
#pragma unroll
        for (int j = 0; j < 2; ++j)
            acc[i][j] = (f32x16)(0.f);

    const int l31 = lane & 31;
    const int hi  = lane >> 5;

    auto COMPUTE = [&](int buf) {
        const char* la = ldsA[buf];
        const char* lb = ldsW[buf];
#pragma unroll
        for (int s = 0; s < 4; ++s) {          // 4 K-slices of 16
            const int ch = s * 2 + hi;         // 16B chunk along K
            short8 af[2], bf[2];
#pragma unroll
            for (int i = 0; i < 2; ++i) {
                int r = wm * 64 + i * 32 + l31;
                af[i] = *(const short8*)(la + r * (BK * 2) + ((ch ^ (r & 7)) << 4));
            }
#pragma unroll
            for (int j = 0; j < 2; ++j) {
                int r = wn * 64 + j * 32 + l31;
                bf[j] = *(const short8*)(lb + r * (BK * 2) + ((ch ^ (r & 7)) << 4));
            }
#pragma unroll
            for (int i = 0; i < 2; ++i)
#pragma unroll
                for (int j = 0; j < 2; ++j)
                    acc[i][j] = __builtin_amdgcn_mfma_f32_32x32x16_bf16(af[i], bf[j], acc[i][j], 0, 0, 0);
        }
    };

    const float* Srow = S + (size_t)tn * SN;

    // ---- prologue
    if (AMODE) AGL(0, 0); else ALD(0);
    WLD(0);
    WRITES(0, Srow[0]);
    if (AMODE == 0) ALD(1);
    WLD(1);
    __syncthreads();

    // ---- main loop: plain 2-phase double-buffer, distance-2 W prefetch
    for (int kt = 0; kt < NTK; ++kt) {
        const int cur = kt & 1;
        const int nxt = cur ^ 1;
        if (AMODE && kt + 1 < NTK) AGL(kt + 1, nxt);
        COMPUTE(cur);
        if (kt + 1 < NTK) {
            WRITES(nxt, Srow[(kt + 1) >> 1]);
            if (kt + 2 < NTK) { if (AMODE == 0) ALD(kt + 2); WLD(kt + 2); }
        }
        __syncthreads();
    }

    // ---- epilogue: 32x32 C/D layout: col=lane&31, row=(reg&3)+8*(reg>>2)+4*hi
#pragma unroll
    for (int i = 0; i < 2; ++i) {
#pragma unroll
        for (int j = 0; j < 2; ++j) {
            float* Cb = C + (size_t)(m0 + wm * 64 + i * 32) * NDIM + (n0 + wn * 64 + j * 32 + l31);
#pragma unroll
            for (int reg = 0; reg < 16; ++reg) {
                int row = (reg & 3) + 8 * (reg >> 2) + 4 * hi;
                Cb[(size_t)row * NDIM] = acc[i][j][reg];
            }
        }
    }
}

extern "C" void kernel_launch(void* const* d_in, const int* in_sizes, int n_in,
                              void* d_out, int out_size, void* d_ws, size_t ws_size,
                              hipStream_t stream) {
    const float* inp = (const float*)d_in[0];   // [1,512,7168] fp32
    const float* w   = (const float*)d_in[1];   // [18432,7168] fp32
    const float* s   = (const float*)d_in[2];   // [144,56] fp32
    float* out       = (float*)d_out;           // [1,512,18432] fp32

    int M = in_sizes[0] / KDIM;                 // 512
    int grid = (M / BM) * (NDIM / BN);          // 576
    int nunits = (M / BM) * NTK * 1024;
    size_t need = (size_t)nunits * 16;

    if (ws_size >= need) {
        __hip_bfloat16* abt = (__hip_bfloat16*)d_ws;
        hipLaunchKernelGGL(a_permute, dim3((nunits + 255) / 256), dim3(256), 0, stream,
                           inp, abt, nunits);
        hipLaunchKernelGGL((fp8lin_gemm<1>), dim3(grid), dim3(256), 0, stream,
                           inp, (const char*)abt, w, s, out, M);
    } else {
        hipLaunchKernelGGL((fp8lin_gemm<0>), dim3(grid), dim3(256), 0, stream,
                           inp, (const char*)nullptr, w, s, out, M);
    }
}